// Round 8
// baseline (414.036 us; speedup 1.0000x reference)
//
#include <hip/hip_runtime.h>
#include <stdint.h>

#define NN 100000
#define NE 3200000
#define KF 256   // in features
#define MF 128   // out features

#define RB 64                         // rows per bucket
#define NB ((NN + RB - 1) / RB)       // 1563 buckets
#define EPB 8192                      // edges per block (partition)
#define PTH 1024                      // part block threads (16 waves)
#define EPT (EPB / PTH)               // 8 edges per thread
#define PGRID ((NE + EPB - 1) / EPB)  // 391
#define SCAPB 2560                    // fixed region capacity per bucket (mean 2048, +11 sigma)
#define RPT 10                        // records per thread in sortgather (2560/256)

typedef __attribute__((ext_vector_type(8))) short bf16x8;
typedef __attribute__((ext_vector_type(4))) float floatx4;

__device__ __forceinline__ unsigned short f2bf(float f) {
  union { float f; unsigned int i; } w; w.f = f;
  unsigned int u = w.i;
  u += 0x7FFFu + ((u >> 16) & 1u);   // round-to-nearest-even
  return (unsigned short)(u >> 16);
}

// ---- Kernel 0: Wt transpose/cast + cursor init ----
__global__ __launch_bounds__(256) void wt_kernel(const float* __restrict__ W,
                                                 unsigned short* __restrict__ Wt,
                                                 unsigned int* __restrict__ cursor) {
  int idx = blockIdx.x * 256 + threadIdx.x;   // 32768 total
  int k = idx >> 7;
  int c = idx & 127;
  Wt[(size_t)c * KF + k] = f2bf(W[(size_t)k * MF + c]);
  if (idx < NB) cursor[idx] = (unsigned int)idx * SCAPB;   // fixed bucket region base
}

// ---- Kernel 1: support = x @ W + b. Col-split waves + T14 register prefetch ----
// Loads for K-chunk kb+1 issue BEFORE the MFMA phase of kb: HBM latency hides
// under barrier+compute instead of being exposed 4x per block.
__global__ __launch_bounds__(256) void gemm_kernel(const float* __restrict__ x,
                                                   const unsigned short* __restrict__ Wt,
                                                   const float* __restrict__ bias,
                                                   unsigned short* __restrict__ support) {
  __shared__ unsigned short Ax[64][72];    // 9.2 KB  (stride 144 B: 2-way bank = free)
  __shared__ unsigned short Wl[128][72];   // 18.4 KB
  const int tid = threadIdx.x;
  const int row0 = blockIdx.x * 64;
  const int lane = tid & 63;
  const int wv = tid >> 6;        // wave owns cols [wv*32, wv*32+32)
  const int m = lane & 15;
  const int quad = lane >> 4;

  floatx4 acc[4][2];              // [row-tile][col-tile within strip]
#pragma unroll
  for (int rt = 0; rt < 4; ++rt)
#pragma unroll
    for (int c2 = 0; c2 < 2; ++c2) acc[rt][c2] = (floatx4){0.f, 0.f, 0.f, 0.f};

  // staging registers (4 float4 of x, 4 uint4 of Wt per thread)
  float4 xr[4];
  uint4  wr[4];
  // prologue: load kb=0
#pragma unroll
  for (int i = 0; i < 4; ++i) {
    int u = tid + i * 256;
    int r = u >> 4, q = u & 15;
    xr[i] = make_float4(0.f, 0.f, 0.f, 0.f);
    if (row0 + r < NN)
      xr[i] = *(const float4*)(x + (size_t)(row0 + r) * KF + q * 4);
  }
#pragma unroll
  for (int i = 0; i < 4; ++i) {
    int u = tid + i * 256;
    int c = u >> 3, kq = u & 7;
    wr[i] = *(const uint4*)(Wt + (size_t)c * KF + kq * 8);
  }

  for (int kb = 0; kb < 4; ++kb) {
    if (kb) __syncthreads();     // previous compute done reading LDS
    // write current chunk regs -> LDS (f2bf here)
#pragma unroll
    for (int i = 0; i < 4; ++i) {
      int u = tid + i * 256;
      int r = u >> 4, q = u & 15;
      ushort4 p;
      p.x = f2bf(xr[i].x); p.y = f2bf(xr[i].y); p.z = f2bf(xr[i].z); p.w = f2bf(xr[i].w);
      *(ushort4*)(&Ax[r][q * 4]) = p;
    }
#pragma unroll
    for (int i = 0; i < 4; ++i) {
      int u = tid + i * 256;
      int c = u >> 3, kq = u & 7;
      *(uint4*)(&Wl[c][kq * 8]) = wr[i];
    }
    // prefetch next chunk into regs (in flight across barrier + MFMA)
    if (kb < 3) {
#pragma unroll
      for (int i = 0; i < 4; ++i) {
        int u = tid + i * 256;
        int r = u >> 4, q = u & 15;
        xr[i] = make_float4(0.f, 0.f, 0.f, 0.f);
        if (row0 + r < NN)
          xr[i] = *(const float4*)(x + (size_t)(row0 + r) * KF + (kb + 1) * 64 + q * 4);
      }
#pragma unroll
      for (int i = 0; i < 4; ++i) {
        int u = tid + i * 256;
        int c = u >> 3, kq = u & 7;
        wr[i] = *(const uint4*)(Wt + (size_t)c * KF + (kb + 1) * 64 + kq * 8);
      }
    }
    __syncthreads();
#pragma unroll
    for (int kc = 0; kc < 2; ++kc) {
      int k0 = kc * 32 + quad * 8;
      bf16x8 af[4];
#pragma unroll
      for (int rt = 0; rt < 4; ++rt)
        af[rt] = *(const bf16x8*)(&Ax[rt * 16 + m][k0]);
#pragma unroll
      for (int c2 = 0; c2 < 2; ++c2) {
        bf16x8 bfv = *(const bf16x8*)(&Wl[(wv * 2 + c2) * 16 + m][k0]);
#pragma unroll
        for (int rt = 0; rt < 4; ++rt)
          acc[rt][c2] = __builtin_amdgcn_mfma_f32_16x16x32_bf16(af[rt], bfv, acc[rt][c2], 0, 0, 0);
      }
    }
  }
#pragma unroll
  for (int c2 = 0; c2 < 2; ++c2) {
    int col = (wv * 2 + c2) * 16 + m;
    float bv = bias[col];
#pragma unroll
    for (int rt = 0; rt < 4; ++rt) {
#pragma unroll
      for (int rg = 0; rg < 4; ++rg) {
        int grow = row0 + rt * 16 + quad * 4 + rg;
        if (grow < NN)
          support[(size_t)grow * MF + col] = f2bf(acc[rt][c2][rg] + bv);
      }
    }
  }
}

// ---- Kernel 2: partition edges into fixed-capacity bucket regions ----
// EPB=8192 (grid 391 covers all CUs); record: key = (row&63)<<17 | col, val bits.
__global__ __launch_bounds__(PTH) void part_kernel(const int* __restrict__ rows,
                                                   const int* __restrict__ cols,
                                                   const float* __restrict__ vals,
                                                   unsigned int* __restrict__ cursor,
                                                   uint2* __restrict__ binned) {
  __shared__ unsigned int hist[NB];
  __shared__ unsigned int base[NB];
  const int tid = threadIdx.x;
  const int e0 = blockIdx.x * EPB;
  for (int i = tid; i < NB; i += PTH) hist[i] = 0u;
  __syncthreads();
  unsigned int pk[EPT];   // row (17b) | rank (13b, <8192) ; 0xFFFFFFFF = invalid
#pragma unroll
  for (int k = 0; k < EPT; ++k) {
    int e = e0 + tid + k * PTH;
    if (e < NE) {
      unsigned int r = (unsigned int)rows[e];
      unsigned int rank = atomicAdd(&hist[r >> 6], 1u);   // within-block rank
      pk[k] = r | (rank << 17);
    } else pk[k] = 0xFFFFFFFFu;
  }
  __syncthreads();
  for (int i = tid; i < NB; i += PTH) {
    unsigned int c = hist[i];
    base[i] = c ? atomicAdd(&cursor[i], c) : 0u;
  }
  __syncthreads();
#pragma unroll
  for (int k = 0; k < EPT; ++k) {
    if (pk[k] != 0xFFFFFFFFu) {
      int e = e0 + tid + k * PTH;
      unsigned int r = pk[k] & 0x1FFFFu;
      unsigned int rank = pk[k] >> 17;
      unsigned int b = r >> 6;
      unsigned int pos = base[b] + rank;
      if (pos < (b + 1u) * SCAPB) {   // capacity guard (never hit at +11 sigma)
        unsigned int key = ((r & 63u) << 17) | (unsigned int)cols[e];
        binned[pos] = make_uint2(key, __float_as_uint(vals[e]));
      }
    }
  }
}

// ---- Kernel 3: fused per-bucket counting sort (LDS) + gather-accumulate ----
// At its measured structural ceiling (~118 us, 352 MB beyond-L2 fetch) — unchanged.
#define FMA4(ev, sv) { \
    float v_ = __uint_as_float((ev).y); \
    a0 = fmaf(v_, __uint_as_float((sv).x << 16), a0); \
    a1 = fmaf(v_, __uint_as_float((sv).x & 0xFFFF0000u), a1); \
    a2 = fmaf(v_, __uint_as_float((sv).y << 16), a2); \
    a3 = fmaf(v_, __uint_as_float((sv).y & 0xFFFF0000u), a3); \
  }
#define SUP(ev) (*(const uint2*)(support_u + (size_t)(ev).x * 64 + hl * 2))

__global__ __launch_bounds__(256) void sortgather_kernel(const unsigned int* __restrict__ cursor,
                                                         const uint2* __restrict__ binned,
                                                         const unsigned int* __restrict__ support_u,
                                                         float* __restrict__ out) {
  __shared__ uint2 stage[SCAPB];           // 20 KiB -> 7 blocks/CU
  __shared__ unsigned int lcnt[RB];
  __shared__ unsigned int lbase[RB + 1];
  const int tid = threadIdx.x;
  const unsigned int start = blockIdx.x * SCAPB;
  unsigned int end = cursor[blockIdx.x];
  if (end > start + SCAPB) end = start + SCAPB;
  if (tid < RB) lcnt[tid] = 0u;
  __syncthreads();
  // pass A: load records, histogram with rank capture (static-indexed reg arrays)
  uint2 rec[RPT];
  unsigned short rk[RPT];
  unsigned short rl_[RPT];
#pragma unroll
  for (int k = 0; k < RPT; ++k) {
    unsigned int i = start + (unsigned int)tid + (unsigned int)k * 256u;
    rec[k] = make_uint2(0u, 0u); rk[k] = 0; rl_[k] = 0xFFFFu;
    if (i < end) {
      rec[k] = binned[i];
      unsigned int rl = rec[k].x >> 17;
      rl_[k] = (unsigned short)rl;
      rk[k] = (unsigned short)atomicAdd(&lcnt[rl], 1u);
    }
  }
  __syncthreads();
  // exclusive scan of the 64 row counts (wave 0)
  if (tid < 64) {
    unsigned int v = lcnt[tid];
    unsigned int inc = v;
#pragma unroll
    for (int d = 1; d < 64; d <<= 1) {
      unsigned int n = __shfl_up(inc, d, 64);
      if (tid >= d) inc += n;
    }
    lbase[tid] = inc - v;
    if (tid == 63) lbase[64] = inc;
  }
  __syncthreads();
  // pass B: scatter into sorted LDS position, strip row bits
#pragma unroll
  for (int k = 0; k < RPT; ++k) {
    if (rl_[k] != 0xFFFFu) {
      unsigned int pos = lbase[rl_[k]] + (unsigned int)rk[k];
      if (pos < SCAPB) stage[pos] = make_uint2(rec[k].x & 0x1FFFFu, rec[k].y);
    }
  }
  __syncthreads();
  // pass C: gather. 8 edges per half-wave per iteration
  const int lane = tid & 63;
  const int wv = tid >> 6;
  const int half = lane >> 5;
  const int hl = lane & 31;
  const int node0 = blockIdx.x * RB;
#pragma unroll 1
  for (int nn = 0; nn < 16; ++nn) {
    const int rl = wv * 16 + nn;
    const int node = node0 + rl;
    unsigned int i = lbase[rl];
    const unsigned int e = lbase[rl + 1];
    float a0 = 0.f, a1 = 0.f, a2 = 0.f, a3 = 0.f;
    for (; i + 16 <= e; i += 16) {
      unsigned int j = i + half * 8;
      uint2 e0 = stage[j + 0];
      uint2 e1 = stage[j + 1];
      uint2 e2 = stage[j + 2];
      uint2 e3 = stage[j + 3];
      uint2 e4 = stage[j + 4];
      uint2 e5 = stage[j + 5];
      uint2 e6 = stage[j + 6];
      uint2 e7 = stage[j + 7];
      uint2 s0 = SUP(e0);
      uint2 s1 = SUP(e1);
      uint2 s2 = SUP(e2);
      uint2 s3 = SUP(e3);
      uint2 s4 = SUP(e4);
      uint2 s5 = SUP(e5);
      uint2 s6 = SUP(e6);
      uint2 s7 = SUP(e7);
      FMA4(e0, s0); FMA4(e1, s1); FMA4(e2, s2); FMA4(e3, s3);
      FMA4(e4, s4); FMA4(e5, s5); FMA4(e6, s6); FMA4(e7, s7);
    }
    if (i + 8 <= e) {
      unsigned int j = i + half * 4;
      uint2 e0 = stage[j + 0];
      uint2 e1 = stage[j + 1];
      uint2 e2 = stage[j + 2];
      uint2 e3 = stage[j + 3];
      uint2 s0 = SUP(e0);
      uint2 s1 = SUP(e1);
      uint2 s2 = SUP(e2);
      uint2 s3 = SUP(e3);
      FMA4(e0, s0); FMA4(e1, s1); FMA4(e2, s2); FMA4(e3, s3);
      i += 8;
    }
    if (i + 4 <= e) {
      unsigned int j = i + half * 2;
      uint2 e0 = stage[j + 0];
      uint2 e1 = stage[j + 1];
      uint2 s0 = SUP(e0);
      uint2 s1 = SUP(e1);
      FMA4(e0, s0); FMA4(e1, s1);
      i += 4;
    }
    if (i + 2 <= e) {
      uint2 e0 = stage[i + half];
      uint2 s0 = SUP(e0);
      FMA4(e0, s0);
      i += 2;
    }
    if (i < e && half == 0) {
      uint2 e0 = stage[i];
      uint2 s0 = SUP(e0);
      FMA4(e0, s0);
    }
    // combine half-waves: lanes 0..31 += lanes 32..63
    a0 += __shfl(a0, hl + 32);
    a1 += __shfl(a1, hl + 32);
    a2 += __shfl(a2, hl + 32);
    a3 += __shfl(a3, hl + 32);
    if (half == 0 && node < NN) {
      float4 o = make_float4(a0, a1, a2, a3);
      *(float4*)(out + (size_t)node * MF + hl * 4) = o;
    }
  }
}

extern "C" void kernel_launch(void* const* d_in, const int* in_sizes, int n_in,
                              void* d_out, int out_size, void* d_ws, size_t ws_size,
                              hipStream_t stream) {
  const float* x    = (const float*)d_in[0];
  const int*   rows = (const int*)d_in[1];
  const int*   cols = (const int*)d_in[2];
  const float* vals = (const float*)d_in[3];
  const float* W    = (const float*)d_in[4];
  const float* bias = (const float*)d_in[5];

  char* ws = (char*)d_ws;
  unsigned short* Wt      = (unsigned short*)ws;                            // 65,536 B
  unsigned short* support = (unsigned short*)(ws + 65536);                  // 25,600,000 B
  uint2*          binned  = (uint2*)(ws + 65536 + 25600000ull);             // 32,010,240 B
  unsigned int*   cursor  = (unsigned int*)(ws + 57675776ull);              // 6,256 B
  // total ws use: ~57.7 MB

  wt_kernel<<<128, 256, 0, stream>>>(W, Wt, cursor);
  gemm_kernel<<<(NN + 63) / 64, 256, 0, stream>>>(x, Wt, bias, support);
  part_kernel<<<PGRID, PTH, 0, stream>>>(rows, cols, vals, cursor, binned);
  sortgather_kernel<<<NB, 256, 0, stream>>>(cursor, binned,
                                            (const unsigned int*)support, (float*)d_out);
}

// Round 9
// 401.169 us; speedup vs baseline: 1.0321x; 1.0321x over previous
//
#include <hip/hip_runtime.h>
#include <stdint.h>

#define NN 100000
#define NE 3200000
#define KF 256   // in features
#define MF 128   // out features

#define RB 64                         // rows per bucket
#define NB ((NN + RB - 1) / RB)       // 1563 buckets
#define EPB 8192                      // edges per block (partition)
#define PTH 1024                      // part block threads (16 waves)
#define EPT (EPB / PTH)               // 8 edges per thread
#define PGRID ((NE + EPB - 1) / EPB)  // 391
#define SCAPB 2560                    // fixed region capacity per bucket (mean 2048, +11 sigma)
#define RPT 10                        // records per thread in sortgather (2560/256)

typedef __attribute__((ext_vector_type(8))) short bf16x8;
typedef __attribute__((ext_vector_type(4))) float floatx4;

__device__ __forceinline__ unsigned short f2bf(float f) {
  union { float f; unsigned int i; } w; w.f = f;
  unsigned int u = w.i;
  u += 0x7FFFu + ((u >> 16) & 1u);   // round-to-nearest-even
  return (unsigned short)(u >> 16);
}

// ---- Kernel 0: Wt transpose/cast + cursor init ----
__global__ __launch_bounds__(256) void wt_kernel(const float* __restrict__ W,
                                                 unsigned short* __restrict__ Wt,
                                                 unsigned int* __restrict__ cursor) {
  int idx = blockIdx.x * 256 + threadIdx.x;   // 32768 total
  int k = idx >> 7;
  int c = idx & 127;
  Wt[(size_t)c * KF + k] = f2bf(W[(size_t)k * MF + c]);
  if (idx < NB) cursor[idx] = (unsigned int)idx * SCAPB;   // fixed bucket region base
}

// ---- Kernel 1: support = x @ W + b. Col-split waves: each wave owns a 32-col strip ----
// (round-5 version: no register prefetch — the vmcnt(0) drain before s_barrier
//  defeats cross-barrier prefetch at HIP level; measured +14.5 us regression)
__global__ __launch_bounds__(256) void gemm_kernel(const float* __restrict__ x,
                                                   const unsigned short* __restrict__ Wt,
                                                   const float* __restrict__ bias,
                                                   unsigned short* __restrict__ support) {
  __shared__ unsigned short Ax[64][72];    // 9.2 KB  (stride 144 B: 2-way bank = free)
  __shared__ unsigned short Wl[128][72];   // 18.4 KB
  const int tid = threadIdx.x;
  const int row0 = blockIdx.x * 64;
  const int lane = tid & 63;
  const int wv = tid >> 6;        // wave owns cols [wv*32, wv*32+32)
  const int m = lane & 15;
  const int quad = lane >> 4;

  floatx4 acc[4][2];              // [row-tile][col-tile within strip]
#pragma unroll
  for (int rt = 0; rt < 4; ++rt)
#pragma unroll
    for (int c2 = 0; c2 < 2; ++c2) acc[rt][c2] = (floatx4){0.f, 0.f, 0.f, 0.f};

  for (int kb = 0; kb < 4; ++kb) {
    if (kb) __syncthreads();
    // stage x: 64 rows x 64 ks -> 1024 float4, 4 per thread
#pragma unroll
    for (int i = 0; i < 4; ++i) {
      int u = tid + i * 256;
      int r = u >> 4;              // 16 float4 per row
      int q = u & 15;
      float4 v = make_float4(0.f, 0.f, 0.f, 0.f);
      if (row0 + r < NN)
        v = *(const float4*)(x + (size_t)(row0 + r) * KF + kb * 64 + q * 4);
      ushort4 p;
      p.x = f2bf(v.x); p.y = f2bf(v.y); p.z = f2bf(v.z); p.w = f2bf(v.w);
      *(ushort4*)(&Ax[r][q * 4]) = p;
    }
    // stage Wt: 128 rows x 64 ks bf16 -> 1024 uint4, 4 per thread
#pragma unroll
    for (int i = 0; i < 4; ++i) {
      int u = tid + i * 256;
      int c = u >> 3;              // 8 uint4 per row
      int kq = u & 7;
      *(uint4*)(&Wl[c][kq * 8]) = *(const uint4*)(Wt + (size_t)c * KF + kb * 64 + kq * 8);
    }
    __syncthreads();
#pragma unroll
    for (int kc = 0; kc < 2; ++kc) {
      int k0 = kc * 32 + quad * 8;
      bf16x8 af[4];
#pragma unroll
      for (int rt = 0; rt < 4; ++rt)
        af[rt] = *(const bf16x8*)(&Ax[rt * 16 + m][k0]);
#pragma unroll
      for (int c2 = 0; c2 < 2; ++c2) {
        bf16x8 bfv = *(const bf16x8*)(&Wl[(wv * 2 + c2) * 16 + m][k0]);
#pragma unroll
        for (int rt = 0; rt < 4; ++rt)
          acc[rt][c2] = __builtin_amdgcn_mfma_f32_16x16x32_bf16(af[rt], bfv, acc[rt][c2], 0, 0, 0);
      }
    }
  }
#pragma unroll
  for (int c2 = 0; c2 < 2; ++c2) {
    int col = (wv * 2 + c2) * 16 + m;
    float bv = bias[col];
#pragma unroll
    for (int rt = 0; rt < 4; ++rt) {
#pragma unroll
      for (int rg = 0; rg < 4; ++rg) {
        int grow = row0 + rt * 16 + quad * 4 + rg;
        if (grow < NN)
          support[(size_t)grow * MF + col] = f2bf(acc[rt][c2][rg] + bv);
      }
    }
  }
}

// ---- Kernel 2: partition edges into fixed-capacity bucket regions ----
// record: key = (row&63)<<17 | col, val bits; rank < 8192 fits bits 17..29.
__global__ __launch_bounds__(PTH) void part_kernel(const int* __restrict__ rows,
                                                   const int* __restrict__ cols,
                                                   const float* __restrict__ vals,
                                                   unsigned int* __restrict__ cursor,
                                                   uint2* __restrict__ binned) {
  __shared__ unsigned int hist[NB];
  __shared__ unsigned int base[NB];
  const int tid = threadIdx.x;
  const int e0 = blockIdx.x * EPB;
  for (int i = tid; i < NB; i += PTH) hist[i] = 0u;
  __syncthreads();
  unsigned int pk[EPT];   // row (17b) | rank (13b) ; 0xFFFFFFFF = invalid
#pragma unroll
  for (int k = 0; k < EPT; ++k) {
    int e = e0 + tid + k * PTH;
    if (e < NE) {
      unsigned int r = (unsigned int)rows[e];
      unsigned int rank = atomicAdd(&hist[r >> 6], 1u);   // within-block rank
      pk[k] = r | (rank << 17);
    } else pk[k] = 0xFFFFFFFFu;
  }
  __syncthreads();
  for (int i = tid; i < NB; i += PTH) {
    unsigned int c = hist[i];
    base[i] = c ? atomicAdd(&cursor[i], c) : 0u;
  }
  __syncthreads();
#pragma unroll
  for (int k = 0; k < EPT; ++k) {
    if (pk[k] != 0xFFFFFFFFu) {
      int e = e0 + tid + k * PTH;
      unsigned int r = pk[k] & 0x1FFFFu;
      unsigned int rank = pk[k] >> 17;
      unsigned int b = r >> 6;
      unsigned int pos = base[b] + rank;
      if (pos < (b + 1u) * SCAPB) {   // capacity guard (never hit at +11 sigma)
        unsigned int key = ((r & 63u) << 17) | (unsigned int)cols[e];
        binned[pos] = make_uint2(key, __float_as_uint(vals[e]));
      }
    }
  }
}

// ---- Kernel 3: fused per-bucket counting sort (LDS) + gather-accumulate ----
// Measured structural ceiling: ~118 us, 352 MB L3-path fetch, invariant across
// occupancy/MLP/EPB changes — L3 random-line throughput bound.
#define FMA4(ev, sv) { \
    float v_ = __uint_as_float((ev).y); \
    a0 = fmaf(v_, __uint_as_float((sv).x << 16), a0); \
    a1 = fmaf(v_, __uint_as_float((sv).x & 0xFFFF0000u), a1); \
    a2 = fmaf(v_, __uint_as_float((sv).y << 16), a2); \
    a3 = fmaf(v_, __uint_as_float((sv).y & 0xFFFF0000u), a3); \
  }
#define SUP(ev) (*(const uint2*)(support_u + (size_t)(ev).x * 64 + hl * 2))

__global__ __launch_bounds__(256) void sortgather_kernel(const unsigned int* __restrict__ cursor,
                                                         const uint2* __restrict__ binned,
                                                         const unsigned int* __restrict__ support_u,
                                                         float* __restrict__ out) {
  __shared__ uint2 stage[SCAPB];           // 20 KiB -> 7 blocks/CU
  __shared__ unsigned int lcnt[RB];
  __shared__ unsigned int lbase[RB + 1];
  const int tid = threadIdx.x;
  const unsigned int start = blockIdx.x * SCAPB;
  unsigned int end = cursor[blockIdx.x];
  if (end > start + SCAPB) end = start + SCAPB;
  if (tid < RB) lcnt[tid] = 0u;
  __syncthreads();
  // pass A: load records, histogram with rank capture (static-indexed reg arrays)
  uint2 rec[RPT];
  unsigned short rk[RPT];
  unsigned short rl_[RPT];
#pragma unroll
  for (int k = 0; k < RPT; ++k) {
    unsigned int i = start + (unsigned int)tid + (unsigned int)k * 256u;
    rec[k] = make_uint2(0u, 0u); rk[k] = 0; rl_[k] = 0xFFFFu;
    if (i < end) {
      rec[k] = binned[i];
      unsigned int rl = rec[k].x >> 17;
      rl_[k] = (unsigned short)rl;
      rk[k] = (unsigned short)atomicAdd(&lcnt[rl], 1u);
    }
  }
  __syncthreads();
  // exclusive scan of the 64 row counts (wave 0)
  if (tid < 64) {
    unsigned int v = lcnt[tid];
    unsigned int inc = v;
#pragma unroll
    for (int d = 1; d < 64; d <<= 1) {
      unsigned int n = __shfl_up(inc, d, 64);
      if (tid >= d) inc += n;
    }
    lbase[tid] = inc - v;
    if (tid == 63) lbase[64] = inc;
  }
  __syncthreads();
  // pass B: scatter into sorted LDS position, strip row bits
#pragma unroll
  for (int k = 0; k < RPT; ++k) {
    if (rl_[k] != 0xFFFFu) {
      unsigned int pos = lbase[rl_[k]] + (unsigned int)rk[k];
      if (pos < SCAPB) stage[pos] = make_uint2(rec[k].x & 0x1FFFFu, rec[k].y);
    }
  }
  __syncthreads();
  // pass C: gather. 8 edges per half-wave per iteration
  const int lane = tid & 63;
  const int wv = tid >> 6;
  const int half = lane >> 5;
  const int hl = lane & 31;
  const int node0 = blockIdx.x * RB;
#pragma unroll 1
  for (int nn = 0; nn < 16; ++nn) {
    const int rl = wv * 16 + nn;
    const int node = node0 + rl;
    unsigned int i = lbase[rl];
    const unsigned int e = lbase[rl + 1];
    float a0 = 0.f, a1 = 0.f, a2 = 0.f, a3 = 0.f;
    for (; i + 16 <= e; i += 16) {
      unsigned int j = i + half * 8;
      uint2 e0 = stage[j + 0];
      uint2 e1 = stage[j + 1];
      uint2 e2 = stage[j + 2];
      uint2 e3 = stage[j + 3];
      uint2 e4 = stage[j + 4];
      uint2 e5 = stage[j + 5];
      uint2 e6 = stage[j + 6];
      uint2 e7 = stage[j + 7];
      uint2 s0 = SUP(e0);
      uint2 s1 = SUP(e1);
      uint2 s2 = SUP(e2);
      uint2 s3 = SUP(e3);
      uint2 s4 = SUP(e4);
      uint2 s5 = SUP(e5);
      uint2 s6 = SUP(e6);
      uint2 s7 = SUP(e7);
      FMA4(e0, s0); FMA4(e1, s1); FMA4(e2, s2); FMA4(e3, s3);
      FMA4(e4, s4); FMA4(e5, s5); FMA4(e6, s6); FMA4(e7, s7);
    }
    if (i + 8 <= e) {
      unsigned int j = i + half * 4;
      uint2 e0 = stage[j + 0];
      uint2 e1 = stage[j + 1];
      uint2 e2 = stage[j + 2];
      uint2 e3 = stage[j + 3];
      uint2 s0 = SUP(e0);
      uint2 s1 = SUP(e1);
      uint2 s2 = SUP(e2);
      uint2 s3 = SUP(e3);
      FMA4(e0, s0); FMA4(e1, s1); FMA4(e2, s2); FMA4(e3, s3);
      i += 8;
    }
    if (i + 4 <= e) {
      unsigned int j = i + half * 2;
      uint2 e0 = stage[j + 0];
      uint2 e1 = stage[j + 1];
      uint2 s0 = SUP(e0);
      uint2 s1 = SUP(e1);
      FMA4(e0, s0); FMA4(e1, s1);
      i += 4;
    }
    if (i + 2 <= e) {
      uint2 e0 = stage[i + half];
      uint2 s0 = SUP(e0);
      FMA4(e0, s0);
      i += 2;
    }
    if (i < e && half == 0) {
      uint2 e0 = stage[i];
      uint2 s0 = SUP(e0);
      FMA4(e0, s0);
    }
    // combine half-waves: lanes 0..31 += lanes 32..63
    a0 += __shfl(a0, hl + 32);
    a1 += __shfl(a1, hl + 32);
    a2 += __shfl(a2, hl + 32);
    a3 += __shfl(a3, hl + 32);
    if (half == 0 && node < NN) {
      float4 o = make_float4(a0, a1, a2, a3);
      *(float4*)(out + (size_t)node * MF + hl * 4) = o;
    }
  }
}

extern "C" void kernel_launch(void* const* d_in, const int* in_sizes, int n_in,
                              void* d_out, int out_size, void* d_ws, size_t ws_size,
                              hipStream_t stream) {
  const float* x    = (const float*)d_in[0];
  const int*   rows = (const int*)d_in[1];
  const int*   cols = (const int*)d_in[2];
  const float* vals = (const float*)d_in[3];
  const float* W    = (const float*)d_in[4];
  const float* bias = (const float*)d_in[5];

  char* ws = (char*)d_ws;
  unsigned short* Wt      = (unsigned short*)ws;                            // 65,536 B
  unsigned short* support = (unsigned short*)(ws + 65536);                  // 25,600,000 B
  uint2*          binned  = (uint2*)(ws + 65536 + 25600000ull);             // 32,010,240 B
  unsigned int*   cursor  = (unsigned int*)(ws + 57675776ull);              // 6,256 B
  // total ws use: ~57.7 MB

  wt_kernel<<<128, 256, 0, stream>>>(W, Wt, cursor);
  gemm_kernel<<<(NN + 63) / 64, 256, 0, stream>>>(x, Wt, bias, support);
  part_kernel<<<PGRID, PTH, 0, stream>>>(rows, cols, vals, cursor, binned);
  sortgather_kernel<<<NB, 256, 0, stream>>>(cursor, binned,
                                            (const unsigned int*)support, (float*)d_out);
}